// Round 2
// baseline (457.973 us; speedup 1.0000x reference)
//
#include <hip/hip_runtime.h>
#include <hip/hip_bf16.h>

namespace {
constexpr int kN    = 8192;
constexpr int kFin  = 512;
constexpr int kFout = 64;
constexpr float kAlpha = 0.2f;
constexpr int kJSplit = 4;                  // j-range split for k_attn
constexpr int kJLen   = kN / kJSplit;       // 2048
constexpr int kChunks = kJLen / 128;        // 16

using bf16x8 = __attribute__((ext_vector_type(8))) short;
using f32x4  = __attribute__((ext_vector_type(4))) float;

__device__ __forceinline__ unsigned short f2bf(float x) {
  return __builtin_bit_cast(unsigned short, __float2bfloat16(x));
}
__device__ __forceinline__ float lrelu(float x) {
  return fmaxf(x, kAlpha * x);   // valid since 0<alpha<1
}
} // namespace

// ---------------------------------------------------------------------------
// k_wt: WT[f][k] = W[k][f]  (fp32, 64x512) — tiny, makes k_linear's W loads
// per-lane contiguous float4 streams.
// ---------------------------------------------------------------------------
__global__ __launch_bounds__(256) void k_wt(const float* __restrict__ W,
                                            float* __restrict__ WT) {
  const int gid = blockIdx.x * 256 + threadIdx.x;   // 0..32767
  const int k = gid >> 6, f = gid & 63;
  WT[(size_t)f * kFin + k] = W[gid];
}

// ---------------------------------------------------------------------------
// k_linear: h = X @ W (fp32 accum); s_src/s_dst; h stored as hTf in
// MFMA-B-fragment order: hTf[jblk(32 rows)][w(4)][lane(64)][e(8)] where
// element = h[j = jblk*32 + (lane>>4)*8 + e][f = w*16 + (lane&15)].
// grid 1024 x 256: block = 8 rows; wave rh owns rows i0+rh*2, +1 across lanes=f.
// ---------------------------------------------------------------------------
__global__ __launch_bounds__(256) void k_linear(
    const float* __restrict__ X, const float* __restrict__ WT, const float* __restrict__ A,
    unsigned short* __restrict__ hTf, float* __restrict__ s_src, float* __restrict__ s_dst)
{
  const int t = threadIdx.x;
  const int rh = t >> 6, f = t & 63;
  const int i0 = blockIdx.x * 8;
  const int r0 = i0 + rh * 2;

  const float* x0 = X + (size_t)r0 * kFin;
  const float* w0 = WT + (size_t)f * kFin;
  float a0 = 0.f, a1 = 0.f;
  for (int k = 0; k < kFin; k += 4) {
    const float4 wv = *(const float4*)(w0 + k);        // per-lane stream (L2)
    const float4 xa = *(const float4*)(x0 + k);        // wave-uniform (broadcast)
    const float4 xb = *(const float4*)(x0 + kFin + k);
#pragma unroll
    for (int j = 0; j < 4; ++j) {
      a0 = fmaf(((const float*)&xa)[j], ((const float*)&wv)[j], a0);
      a1 = fmaf(((const float*)&xb)[j], ((const float*)&wv)[j], a1);
    }
  }

  const float asrc = A[f], adst = A[kFout + f];
  float accs[2] = {a0, a1};
#pragma unroll
  for (int r = 0; r < 2; ++r) {
    float vs = accs[r] * asrc;
    float vd = accs[r] * adst;
#pragma unroll
    for (int off = 32; off > 0; off >>= 1) {
      vs += __shfl_xor(vs, off, 64);
      vd += __shfl_xor(vd, off, 64);
    }
    if (f == 0) { s_src[r0 + r] = vs; s_dst[r0 + r] = vd; }
  }

  // stage h (bf16) then emit the block's 1 KB slice of hTf, coalesced.
  __shared__ unsigned short h_sm[8][64];
  h_sm[rh * 2 + 0][f] = f2bf(a0);
  h_sm[rh * 2 + 1][f] = f2bf(a1);
  __syncthreads();
  if (t < 64) {
    const int w = t >> 4, fl = t & 15;
    const int jblk = i0 >> 5, q = (i0 >> 3) & 3;   // which 8-row slice of the jblk
    const int lane = q * 16 + fl;
    bf16x8 v;
#pragma unroll
    for (int e = 0; e < 8; ++e) v[e] = (short)h_sm[e][w * 16 + fl];
    *(bf16x8*)(hTf + (((size_t)jblk * 4 + w) * 64 + lane) * 8) = v;
  }
}

// ---------------------------------------------------------------------------
// k_smax: S = max_j s_dst[j]
// ---------------------------------------------------------------------------
__global__ __launch_bounds__(1024) void k_smax(const float* __restrict__ s_dst,
                                               float* __restrict__ Sout)
{
  __shared__ float red[16];
  float m = -3.4e38f;
  for (int i = threadIdx.x; i < kN; i += 1024) m = fmaxf(m, s_dst[i]);
#pragma unroll
  for (int off = 32; off > 0; off >>= 1) m = fmaxf(m, __shfl_xor(m, off, 64));
  if ((threadIdx.x & 63) == 0) red[threadIdx.x >> 6] = m;
  __syncthreads();
  if (threadIdx.x == 0) {
    float s = red[0];
#pragma unroll
    for (int i = 1; i < 16; ++i) s = fmaxf(s, red[i]);
    *Sout = s;
  }
}

// ---------------------------------------------------------------------------
// k_attn: partial fused mask+softmax+PV over a quarter of the j-range.
// grid 2048 (= 512 row-blocks x 4 j-quarters), 256 thr. BJ=128, 16 chunks.
// P double-buffered in LDS (one barrier/chunk); B-fragments loaded straight
// from hTf (L2-resident, coalesced) — no H staging.
// Outputs: accp[b][16][64] fp32 partial PV, lp[b][16] fp32 partial denom.
// ---------------------------------------------------------------------------
__global__ __launch_bounds__(256) void k_attn(
    const int* __restrict__ adj, const unsigned short* __restrict__ hTf,
    const float* __restrict__ s_src, const float* __restrict__ s_dst,
    const float* __restrict__ Sp, float* __restrict__ accp, float* __restrict__ lp)
{
  const int t = threadIdx.x;
  const int wv = t >> 6, lane = t & 63;
  const int b = blockIdx.x;
  const int i0 = (b >> 2) * 16;
  const int jbase = (b & 3) * kJLen;
  const int pr = t >> 4, jb = t & 15;

  __shared__ unsigned short Plds[2][16][136];   // 8.7 KB; stride 136 -> 2-way max

  const float S = *Sp;
  const float ssrc = s_src[i0 + pr];
  const float mr = lrelu(ssrc + S);             // >= every score in the row

  float l_acc = 0.f;
  f32x4 acc = {0.f, 0.f, 0.f, 0.f};

  const size_t adj_off = (size_t)(i0 + pr) * kN + jbase + (size_t)jb * 8;
  int4 A0, A1; float4 d0, d1;
  auto load_chunk = [&](int c) {
    const int4* ap = (const int4*)(adj + adj_off + (size_t)c * 128);
    A0 = ap[0]; A1 = ap[1];
    const float* dp = s_dst + jbase + c * 128 + jb * 8;
    d0 = ((const float4*)dp)[0];
    d1 = ((const float4*)dp)[1];
  };
  load_chunk(0);

  const int mrow = lane & 15, quad = lane >> 4;
  // B-fragment base: hTf element ((jblk*4 + wv)*64 + lane)*8, jblk = jbase/32 + c*4 + ks
  const unsigned short* hptr =
      hTf + (((size_t)(jbase >> 5) * 4 + wv) * 64 + lane) * 8;

  for (int c = 0; c < kChunks; ++c) {
    float pv[8];
    {
      const int* aa = (const int*)&A0;
      const float* dd = (const float*)&d0;
#pragma unroll
      for (int j = 0; j < 4; ++j) {
        const float e = lrelu(ssrc + dd[j]);
        pv[j] = aa[j] > 0 ? __expf(e - mr) : 0.f;
      }
      aa = (const int*)&A1; dd = (const float*)&d1;
#pragma unroll
      for (int j = 0; j < 4; ++j) {
        const float e = lrelu(ssrc + dd[j]);
        pv[4 + j] = aa[j] > 0 ? __expf(e - mr) : 0.f;
      }
    }
    bf16x8 ps;
#pragma unroll
    for (int j = 0; j < 8; ++j) {
      l_acc += pv[j];
      ps[j] = (short)f2bf(pv[j]);
    }
    *(bf16x8*)&Plds[c & 1][pr][jb * 8] = ps;
    if (c + 1 < kChunks) load_chunk(c + 1);    // prefetch while MFMA phase runs
    __syncthreads();
#pragma unroll
    for (int ks = 0; ks < 4; ++ks) {
      const bf16x8 av = *(const bf16x8*)&Plds[c & 1][mrow][ks * 32 + quad * 8];
      const bf16x8 bv = *(const bf16x8*)(hptr + ((size_t)c * 4 + ks) * 2048);
      acc = __builtin_amdgcn_mfma_f32_16x16x32_bf16(av, bv, acc, 0, 0, 0);
    }
    // no second barrier: next write targets the other P buffer
  }

  // partial denominator: 16 lanes (same pr) reduce
  float lv = l_acc;
  lv += __shfl_xor(lv, 8, 64);
  lv += __shfl_xor(lv, 4, 64);
  lv += __shfl_xor(lv, 2, 64);
  lv += __shfl_xor(lv, 1, 64);
  if (jb == 0) lp[(size_t)b * 16 + pr] = lv;

  // partial PV tile: accp[b][row][col], row = quad*4+reg, col = wv*16+mrow
  float* ab = accp + (size_t)b * 16 * 64;
#pragma unroll
  for (int reg = 0; reg < 4; ++reg) {
    ab[(quad * 4 + reg) * 64 + wv * 16 + mrow] = acc[reg];
  }
}

// ---------------------------------------------------------------------------
// k_comb: out[i][f] = elu( (sum_q accp) / (sum_q lp) )
// ---------------------------------------------------------------------------
__global__ __launch_bounds__(256) void k_comb(const float* __restrict__ accp,
                                              const float* __restrict__ lp,
                                              float* __restrict__ out)
{
  const int gid = blockIdx.x * 256 + threadIdx.x;   // 0..524287
  const int i = gid >> 6, f = gid & 63;
  const int ib = i >> 4, il = i & 15;
  const int b0 = ib * kJSplit;
  float a = 0.f, l = 0.f;
#pragma unroll
  for (int q = 0; q < kJSplit; ++q) {
    a += accp[((size_t)(b0 + q) * 16 + il) * 64 + f];
    l += lp[(size_t)(b0 + q) * 16 + il];
  }
  float v = a / l;
  v = v > 0.f ? v : __expf(v) - 1.f;
  out[gid] = v;
}

extern "C" void kernel_launch(void* const* d_in, const int* in_sizes, int n_in,
                              void* d_out, int out_size, void* d_ws, size_t ws_size,
                              hipStream_t stream) {
  const float* X   = (const float*)d_in[0];   // [8192][512]
  const int*   adj = (const int*)d_in[1];     // [8192][8192]
  const float* W   = (const float*)d_in[2];   // [512][64]
  const float* A   = (const float*)d_in[3];   // [128]
  float* out = (float*)d_out;                 // [8192][64] fp32

  char* ws = (char*)d_ws;
  unsigned short* hTf = (unsigned short*)ws;              ws += (size_t)kN * kFout * 2;   // 1 MB
  float* WT    = (float*)ws;                              ws += (size_t)kFout * kFin * 4; // 128 KB
  float* s_src = (float*)ws;                              ws += kN * 4;
  float* s_dst = (float*)ws;                              ws += kN * 4;
  float* Sp    = (float*)ws;                              ws += 256;
  float* accp  = (float*)ws;                              ws += (size_t)(kN / 16) * kJSplit * 16 * 64 * 4; // 8 MB
  float* lp    = (float*)ws;                              // 2048*16*4 = 128 KB

  k_wt    <<<kFin * kFout / 256, 256, 0, stream>>>(W, WT);
  k_linear<<<kN / 8, 256, 0, stream>>>(X, WT, A, hTf, s_src, s_dst);
  k_smax  <<<1, 1024, 0, stream>>>(s_dst, Sp);
  k_attn  <<<(kN / 16) * kJSplit, 256, 0, stream>>>(adj, hTf, s_src, s_dst, Sp, accp, lp);
  k_comb  <<<kN * kFout / 256, 256, 0, stream>>>(accp, lp, out);
}